// Round 19
// baseline (81.592 us; speedup 1.0000x reference)
//
#include <hip/hip_runtime.h>
#include <math.h>

#define T_TOK 32768
#define DIM   2048
#define E_N   64
#define KP    2048   // padded K (k==0 column is zero)

typedef float v4f    __attribute__((ext_vector_type(4)));
typedef float f32x4  __attribute__((ext_vector_type(4)));
typedef _Float16 f16x8 __attribute__((ext_vector_type(8)));
typedef __fp16 h2      __attribute__((ext_vector_type(2)));
typedef unsigned int u32x4 __attribute__((ext_vector_type(4)));

// fragment-linear W: wl[kc][s][t][lane][8]  (64 kc x 2 s x 4 t x 64 lanes x 8)
#define CHUNK_USH 4096                    // ushorts per kc chunk (8 KB)
#define WL_USHORTS (64 * CHUNK_USH)       // 512 KB total
#define RSCALE 4096.0f                    // residual pre-scale (2^12)
#define RINV   (1.0f / 4096.0f)

__device__ __forceinline__ unsigned short h2u(_Float16 h) {
  union { _Float16 h; unsigned short u; } c; c.h = h; return c.u;
}
__device__ __forceinline__ f16x8 ldh(const unsigned short* p) {
  union { u32x4 u; f16x8 h; } c; c.u = *(const u32x4*)p; return c.h;
}
__device__ __forceinline__ f16x8 packh(h2 a, h2 b, h2 c, h2 d) {
  union { h2 q[4]; f16x8 h; } t; t.q[0] = a; t.q[1] = b; t.q[2] = c; t.q[3] = d;
  return t.h;
}
__device__ __forceinline__ void async16(const void* g, void* l) {
  __builtin_amdgcn_global_load_lds((const __attribute__((address_space(1))) void*)g,
                                   (__attribute__((address_space(3))) void*)l,
                                   16, 0, 0);
}

// ---------------- kernel 0: W -> fragment-linear 2-way fp16 split ----------------
// wl[kc][s][t][lane][j]: expert e = t*16 + (lane&15), k = kc*32 + (lane>>4)*8 + j.
// s=0: fp16(w) (RNE); s=1: fp16((w - f32(s0)) * 2^12) (residual, pre-scaled normal).
__global__ __launch_bounds__(256) void k_prep(const float* __restrict__ w,
                                              unsigned short* __restrict__ wl) {
  int idx = blockIdx.x * 256 + threadIdx.x;    // 0 .. 262143
  int kc = idx >> 12;
  int r  = idx & 4095;
  int s  = r >> 11;
  int r2 = r & 2047;
  int t  = r2 >> 9;
  int r3 = r2 & 511;
  int lane = r3 >> 3;
  int j    = r3 & 7;
  int e = t * 16 + (lane & 15);
  int k = kc * 32 + (lane >> 4) * 8 + j;
  float f = (k == 0) ? 0.f : w[e * 2047 + (k - 1)];
  _Float16 h0 = (_Float16)f;                 // RNE
  float res = f - (float)h0;                 // exact
  _Float16 h1 = (_Float16)(res * RSCALE);    // RNE, normal-range
  wl[idx] = (s == 0) ? h2u(h0) : h2u(h1);
}

// ---------------- kernel 1: fused logits + routing ----------------
// Block = 8 waves = 2 tp (32-token tiles) x 4 kh (512-k quarters); grid 512
// = 2 blocks/CU -> 16 waves/CU = 4 waves/SIMD (R16's TLP) while each wave
// keeps R17's 32-token W-amortized inner loop. Per step the block stages all
// 4 quarter-chunks (32 KB, double-buffered 64 KB); counted vmcnt(4) + raw
// s_barrier keeps this step's x loads in flight (R18-verified). 16 steps/wave
// (barrier count halved). Epilogue: 4-way kh reduce in 3 fixed-order LDS
// stages -> lgt -> fused routing (R13-R18-verified math throughout).
__global__ __launch_bounds__(512, 2) void k_logits(const float* __restrict__ x,
                                                   const unsigned short* __restrict__ wl,
                                                   const float* __restrict__ bias,
                                                   float* __restrict__ out_w,
                                                   float* __restrict__ out_i) {
  __shared__ union ShMem {
    unsigned short wbuf[2][4][CHUNK_USH];   // [buf][kh][..] 64 KB
    struct { float red[2][4][4][4][64]; float lgt[E_N][68]; } ep;  // 49.4 KB
  } sh;
  const int tid  = threadIdx.x;
  const int lane = tid & 63;
  const int l15  = lane & 15;
  const int w8   = tid >> 6;           // 0..7
  const int tp   = w8 & 1;             // token-pair tile (32 tokens)
  const int kh   = w8 >> 1;            // k-quarter (512 k)
  const int tok0 = blockIdx.x * 64 + tp * 32;
  const int kq   = (lane >> 4) * 8;

  const float* xr0 = x + (size_t)(tok0 + l15) * DIM + kh * 512 + kq;   // tg0
  const float* xr1 = xr0 + (size_t)16 * DIM;                           // tg1

  // staging: q = tid>>7 stages quarter-chunk (q*16 + c); lane-linear 16B dest
  const int q   = tid >> 7;            // 0..3
  const int t128 = tid & 127;
  auto stage = [&](int c, int b) {
    const unsigned short* src = wl + (size_t)(q * 16 + c) * CHUNK_USH;
#pragma unroll
    for (int i = 0; i < 4; ++i)
      async16(src + (i * 128 + t128) * 8, &sh.wbuf[b][q][(i * 128 + t128) * 8]);
  };

  f32x4 acc0[2][4], acc1[2][4];
#pragma unroll
  for (int g = 0; g < 2; ++g)
#pragma unroll
    for (int t = 0; t < 4; ++t) { acc0[g][t] = (f32x4)(0.f); acc1[g][t] = (f32x4)(0.f); }

  // split helper: 8 floats -> main f16x8 + residual f16x8 (pre-scaled 2^12)
  auto split = [&](v4f s0, v4f s1, f16x8& x0, f16x8& x1) {
    h2 q0 = __builtin_amdgcn_cvt_pkrtz(s0.x, s0.y);
    h2 q1 = __builtin_amdgcn_cvt_pkrtz(s0.z, s0.w);
    h2 q2 = __builtin_amdgcn_cvt_pkrtz(s1.x, s1.y);
    h2 q3 = __builtin_amdgcn_cvt_pkrtz(s1.z, s1.w);
    float r0 = (s0.x - (float)q0.x) * RSCALE, r1 = (s0.y - (float)q0.y) * RSCALE;
    float r2 = (s0.z - (float)q1.x) * RSCALE, r3 = (s0.w - (float)q1.y) * RSCALE;
    float r4 = (s1.x - (float)q2.x) * RSCALE, r5 = (s1.y - (float)q2.y) * RSCALE;
    float r6 = (s1.z - (float)q3.x) * RSCALE, r7 = (s1.w - (float)q3.y) * RSCALE;
    h2 u0 = __builtin_amdgcn_cvt_pkrtz(r0, r1);
    h2 u1 = __builtin_amdgcn_cvt_pkrtz(r2, r3);
    h2 u2 = __builtin_amdgcn_cvt_pkrtz(r4, r5);
    h2 u3 = __builtin_amdgcn_cvt_pkrtz(r6, r7);
    x0 = packh(q0, q1, q2, q3);
    x1 = packh(u0, u1, u2, u3);
  };

  // one step: split both token-groups -> reload slots for chunk xc -> 8 LDS
  // frag reads (shared by both groups) -> 24 MFMA -> vmcnt(4) + RAW barrier.
  auto step = [&](v4f& s0, v4f& s1, v4f& s2, v4f& s3, int rb, int sc, int sb, int xc) {
    if (sc < 16) stage(sc, sb);
    f16x8 x0a, x1a, x0b, x1b;
    split(s0, s1, x0a, x1a);
    split(s2, s3, x0b, x1b);
    // slots dead: reload for chunk xc (2-step distance; dummy at tail)
    const float* n0 = xr0 + ((xc < 16) ? xc * 32 : 0);
    const float* n1 = xr1 + ((xc < 16) ? xc * 32 : 0);
    s0 = *(const v4f*)(n0);
    s1 = *(const v4f*)(n0 + 4);
    s2 = *(const v4f*)(n1);
    s3 = *(const v4f*)(n1 + 4);
    // 8 fragment reads from this wave's k-quarter (ds_read_b128, 1 KB each)
    f16x8 wf[2][4];
#pragma unroll
    for (int s = 0; s < 2; ++s)
#pragma unroll
      for (int t = 0; t < 4; ++t)
        wf[s][t] = ldh(&sh.wbuf[rb][kh][(s * 4 + t) * 512 + lane * 8]);
    // token-group 0: 3 passes (residuals into acc1, main into acc0)
#pragma unroll
    for (int t = 0; t < 4; ++t)
      acc1[0][t] = __builtin_amdgcn_mfma_f32_16x16x32_f16(wf[1][t], x0a, acc1[0][t], 0, 0, 0);
#pragma unroll
    for (int t = 0; t < 4; ++t)
      acc1[0][t] = __builtin_amdgcn_mfma_f32_16x16x32_f16(wf[0][t], x1a, acc1[0][t], 0, 0, 0);
#pragma unroll
    for (int t = 0; t < 4; ++t)
      acc0[0][t] = __builtin_amdgcn_mfma_f32_16x16x32_f16(wf[0][t], x0a, acc0[0][t], 0, 0, 0);
    // token-group 1
#pragma unroll
    for (int t = 0; t < 4; ++t)
      acc1[1][t] = __builtin_amdgcn_mfma_f32_16x16x32_f16(wf[1][t], x0b, acc1[1][t], 0, 0, 0);
#pragma unroll
    for (int t = 0; t < 4; ++t)
      acc1[1][t] = __builtin_amdgcn_mfma_f32_16x16x32_f16(wf[0][t], x1b, acc1[1][t], 0, 0, 0);
#pragma unroll
    for (int t = 0; t < 4; ++t)
      acc0[1][t] = __builtin_amdgcn_mfma_f32_16x16x32_f16(wf[0][t], x0b, acc0[1][t], 0, 0, 0);
    // counted wait: drains this step's 4 stage loads; leaves this step's 4 x
    // loads in flight ACROSS the raw barrier (R18-verified pattern).
    asm volatile("s_waitcnt vmcnt(4)" ::: "memory");
    __builtin_amdgcn_s_barrier();
    asm volatile("" ::: "memory");
  };

  // x slots: a* = even chunks, b* = odd chunks (2-step issue-to-use distance)
  v4f a0 = *(const v4f*)(xr0);
  v4f a1 = *(const v4f*)(xr0 + 4);
  v4f a2 = *(const v4f*)(xr1);
  v4f a3 = *(const v4f*)(xr1 + 4);
  v4f b0 = *(const v4f*)(xr0 + 32);
  v4f b1 = *(const v4f*)(xr0 + 36);
  v4f b2 = *(const v4f*)(xr1 + 32);
  v4f b3 = *(const v4f*)(xr1 + 36);

  stage(0, 0);
  asm volatile("s_waitcnt vmcnt(0)" ::: "memory");
  __syncthreads();

  for (int cc = 0; cc < 16; cc += 2) {
    step(a0, a1, a2, a3, 0, cc + 1, 1, cc + 2);   // chunk cc   (reads buf0)
    step(b0, b1, b2, b3, 1, cc + 2, 0, cc + 3);   // chunk cc+1 (reads buf1)
  }

  // ---- epilogue: combine splits, 4-way kh reduce, lgt, fused routing ----
  float comb[2][4][4];
#pragma unroll
  for (int g = 0; g < 2; ++g)
#pragma unroll
    for (int t = 0; t < 4; ++t)
#pragma unroll
      for (int r = 0; r < 4; ++r)
        comb[g][t][r] = acc0[g][t][r] + acc1[g][t][r] * RINV;

  const int tg0 = tp * 2;   // token-group base for this wave
  // stage 1: kh=2 -> red[0], kh=3 -> red[1]
  if (kh >= 2) {
#pragma unroll
    for (int g = 0; g < 2; ++g)
#pragma unroll
      for (int t = 0; t < 4; ++t)
#pragma unroll
        for (int r = 0; r < 4; ++r)
          sh.ep.red[kh - 2][tg0 + g][t][r][lane] = comb[g][t][r];
  }
  __syncthreads();
  // stage 2: kh=0 += red[0] (kh=2's), kh=1 += red[1] (kh=3's)
  if (kh < 2) {
#pragma unroll
    for (int g = 0; g < 2; ++g)
#pragma unroll
      for (int t = 0; t < 4; ++t)
#pragma unroll
        for (int r = 0; r < 4; ++r)
          comb[g][t][r] += sh.ep.red[kh][tg0 + g][t][r][lane];
  }
  __syncthreads();
  // stage 3: kh=1 -> red[0]
  if (kh == 1) {
#pragma unroll
    for (int g = 0; g < 2; ++g)
#pragma unroll
      for (int t = 0; t < 4; ++t)
#pragma unroll
        for (int r = 0; r < 4; ++r)
          sh.ep.red[0][tg0 + g][t][r][lane] = comb[g][t][r];
  }
  __syncthreads();
  // stage 4: kh=0 adds and writes lgt
  if (kh == 0) {
#pragma unroll
    for (int g = 0; g < 2; ++g)
#pragma unroll
      for (int t = 0; t < 4; ++t)
#pragma unroll
        for (int r = 0; r < 4; ++r) {
          const float v = comb[g][t][r] + sh.ep.red[0][tg0 + g][t][r][lane];
          const int e = t * 16 + (lane >> 4) * 4 + r;
          sh.ep.lgt[e][(tg0 + g) * 16 + l15] = v;
        }
  }
  __syncthreads();

  // routing: thread tid<64 handles token blockIdx*64 + tid (R13-R18-verified)
  if (tid < 64) {
    const int row = blockIdx.x * 64 + tid;

    float sb[E_N];
#pragma unroll
    for (int e = 0; e < E_N; ++e)
      sb[e] = 1.f / (1.f + expf(-sh.ep.lgt[e][tid])) + bias[e];

    float gs[8];
#pragma unroll
    for (int g = 0; g < 8; ++g) {
      float m1 = -__builtin_inff(), m2 = -__builtin_inff();
#pragma unroll
      for (int j = 0; j < 8; ++j) {
        float v = sb[g * 8 + j];
        if (v > m1) { m2 = m1; m1 = v; }
        else if (v > m2) { m2 = v; }
      }
      gs[g] = m1 + m2;
    }

    unsigned gmask = 0;
#pragma unroll
    for (int tsel = 0; tsel < 4; ++tsel) {
      float best = -__builtin_inff(); int bi = 0;
#pragma unroll
      for (int g = 0; g < 8; ++g) {
        bool avail = ((gmask >> g) & 1u) == 0u;
        if (avail && gs[g] > best) { best = gs[g]; bi = g; }
      }
      gmask |= (1u << bi);
    }

    unsigned long long tm = 0ull;
#pragma unroll
    for (int g = 0; g < 8; ++g)
      if (((gmask >> g) & 1u) == 0u) tm |= (0xFFull << (8 * g));

    float wv[8]; int io[8]; float wsum = 0.f;
#pragma unroll
    for (int tsel = 0; tsel < 8; ++tsel) {
      float best = -__builtin_inff(); int bi = 0;
#pragma unroll
      for (int e = 0; e < E_N; ++e) {
        bool avail = ((tm >> e) & 1ull) == 0ull;
        if (avail && sb[e] > best) { best = sb[e]; bi = e; }
      }
      tm |= (1ull << bi);
      float sv = best - bias[bi];
      wv[tsel] = sv; io[tsel] = bi; wsum += sv;
    }

    const float scale = 2.5f / wsum;
    float4 w0 = make_float4(wv[0] * scale, wv[1] * scale, wv[2] * scale, wv[3] * scale);
    float4 w1 = make_float4(wv[4] * scale, wv[5] * scale, wv[6] * scale, wv[7] * scale);
    float4 i0 = make_float4((float)io[0], (float)io[1], (float)io[2], (float)io[3]);
    float4 i1 = make_float4((float)io[4], (float)io[5], (float)io[6], (float)io[7]);
    *(float4*)(out_w + (size_t)row * 8)     = w0;
    *(float4*)(out_w + (size_t)row * 8 + 4) = w1;
    *(float4*)(out_i + (size_t)row * 8)     = i0;
    *(float4*)(out_i + (size_t)row * 8 + 4) = i1;
  }
}

extern "C" void kernel_launch(void* const* d_in, const int* in_sizes, int n_in,
                              void* d_out, int out_size, void* d_ws, size_t ws_size,
                              hipStream_t stream) {
  const float* x    = (const float*)d_in[0];
  const float* wgt  = (const float*)d_in[1];
  const float* bias = (const float*)d_in[2];
  float* out = (float*)d_out;
  unsigned short* wlp = (unsigned short*)d_ws;

  k_prep  <<<WL_USHORTS / 256, 256, 0, stream>>>(wgt, wlp);
  k_logits<<<T_TOK / 64,       512, 0, stream>>>(x, wlp, bias,
                                                 out, out + (size_t)T_TOK * 8);
}

// Round 20
// 72.594 us; speedup vs baseline: 1.1239x; 1.1239x over previous
//
#include <hip/hip_runtime.h>
#include <math.h>

#define T_TOK 32768
#define DIM   2048
#define E_N   64
#define KP    2048   // padded K (k==0 column is zero)

typedef float v4f    __attribute__((ext_vector_type(4)));
typedef float f32x4  __attribute__((ext_vector_type(4)));
typedef _Float16 f16x8 __attribute__((ext_vector_type(8)));
typedef __fp16 h2      __attribute__((ext_vector_type(2)));
typedef unsigned int u32x4 __attribute__((ext_vector_type(4)));

// fragment-linear W: wl[kc][s][t][lane][8]  (64 kc x 2 s x 4 t x 64 lanes x 8)
#define CHUNK_USH 4096                    // ushorts per kc chunk (8 KB)
#define WL_USHORTS (64 * CHUNK_USH)       // 512 KB total
#define RSCALE 4096.0f                    // residual pre-scale (2^12)
#define RINV   (1.0f / 4096.0f)

__device__ __forceinline__ unsigned short h2u(_Float16 h) {
  union { _Float16 h; unsigned short u; } c; c.h = h; return c.u;
}
__device__ __forceinline__ f16x8 ldh(const unsigned short* p) {
  union { u32x4 u; f16x8 h; } c; c.u = *(const u32x4*)p; return c.h;
}
__device__ __forceinline__ f16x8 packh(h2 a, h2 b, h2 c, h2 d) {
  union { h2 q[4]; f16x8 h; } t; t.q[0] = a; t.q[1] = b; t.q[2] = c; t.q[3] = d;
  return t.h;
}
__device__ __forceinline__ void async16(const void* g, void* l) {
  __builtin_amdgcn_global_load_lds((const __attribute__((address_space(1))) void*)g,
                                   (__attribute__((address_space(3))) void*)l,
                                   16, 0, 0);
}

// ---------------- kernel 0: W -> fragment-linear 2-way fp16 split ----------------
// wl[kc][s][t][lane][j]: expert e = t*16 + (lane&15), k = kc*32 + (lane>>4)*8 + j.
// s=0: fp16(w) (RNE); s=1: fp16((w - f32(s0)) * 2^12) (residual, pre-scaled normal).
__global__ __launch_bounds__(256) void k_prep(const float* __restrict__ w,
                                              unsigned short* __restrict__ wl) {
  int idx = blockIdx.x * 256 + threadIdx.x;    // 0 .. 262143
  int kc = idx >> 12;
  int r  = idx & 4095;
  int s  = r >> 11;
  int r2 = r & 2047;
  int t  = r2 >> 9;
  int r3 = r2 & 511;
  int lane = r3 >> 3;
  int j    = r3 & 7;
  int e = t * 16 + (lane & 15);
  int k = kc * 32 + (lane >> 4) * 8 + j;
  float f = (k == 0) ? 0.f : w[e * 2047 + (k - 1)];
  _Float16 h0 = (_Float16)f;                 // RNE
  float res = f - (float)h0;                 // exact
  _Float16 h1 = (_Float16)(res * RSCALE);    // RNE, normal-range
  wl[idx] = (s == 0) ? h2u(h0) : h2u(h1);
}

// ---------------- kernel 1: fused logits + routing ----------------
// R18-verified optimum of this structure family (R17 neutral, R19 regression
// bracket it): wave = 32 tokens x 64 experts x k-half; 4 waves/block; 512
// blocks (2/CU); LDS-staged double-buffered 8 KB chunk pairs; 2-step x
// prefetch; counted vmcnt(4) + RAW s_barrier keeps this step's x loads in
// flight across the barrier (the compiler's __syncthreads would force a
// vmcnt(0) full drain). fp16 2-way split math (verified R16-R19).
__global__ __launch_bounds__(256, 2) void k_logits(const float* __restrict__ x,
                                                   const unsigned short* __restrict__ wl,
                                                   const float* __restrict__ bias,
                                                   float* __restrict__ out_w,
                                                   float* __restrict__ out_i) {
  __shared__ union ShMem {
    unsigned short wbuf[2][2][CHUNK_USH];   // [buf][kh][..] 32 KB
    struct { float red[4][4][4][64]; float lgt[E_N][65]; } ep;  // 32.6 KB
  } sh;
  const int tid  = threadIdx.x;
  const int lane = tid & 63;
  const int l15  = lane & 15;
  const int w4   = tid >> 6;           // 0..3
  const int tp   = w4 & 1;             // token-pair tile (32 tokens)
  const int kh   = w4 >> 1;            // k-half
  const int tok0 = blockIdx.x * 64 + tp * 32;
  const int kq   = (lane >> 4) * 8;

  const float* xr0 = x + (size_t)(tok0 + l15) * DIM + kh * 1024 + kq;       // tg0
  const float* xr1 = xr0 + (size_t)16 * DIM;                                 // tg1

  // staging: half = tid>>7 stages chunk (c + half*32); lane-linear 16B dest
  const int half = tid >> 7;
  const int t128 = tid & 127;
  auto stage = [&](int c, int b) {
    const unsigned short* src = wl + (size_t)(c + half * 32) * CHUNK_USH;
#pragma unroll
    for (int i = 0; i < 4; ++i)
      async16(src + (i * 128 + t128) * 8, &sh.wbuf[b][half][(i * 128 + t128) * 8]);
  };

  f32x4 acc0[2][4], acc1[2][4];
#pragma unroll
  for (int g = 0; g < 2; ++g)
#pragma unroll
    for (int t = 0; t < 4; ++t) { acc0[g][t] = (f32x4)(0.f); acc1[g][t] = (f32x4)(0.f); }

  // split helper: 8 floats -> main f16x8 + residual f16x8 (pre-scaled 2^12)
  auto split = [&](v4f s0, v4f s1, f16x8& x0, f16x8& x1) {
    h2 q0 = __builtin_amdgcn_cvt_pkrtz(s0.x, s0.y);
    h2 q1 = __builtin_amdgcn_cvt_pkrtz(s0.z, s0.w);
    h2 q2 = __builtin_amdgcn_cvt_pkrtz(s1.x, s1.y);
    h2 q3 = __builtin_amdgcn_cvt_pkrtz(s1.z, s1.w);
    float r0 = (s0.x - (float)q0.x) * RSCALE, r1 = (s0.y - (float)q0.y) * RSCALE;
    float r2 = (s0.z - (float)q1.x) * RSCALE, r3 = (s0.w - (float)q1.y) * RSCALE;
    float r4 = (s1.x - (float)q2.x) * RSCALE, r5 = (s1.y - (float)q2.y) * RSCALE;
    float r6 = (s1.z - (float)q3.x) * RSCALE, r7 = (s1.w - (float)q3.y) * RSCALE;
    h2 u0 = __builtin_amdgcn_cvt_pkrtz(r0, r1);
    h2 u1 = __builtin_amdgcn_cvt_pkrtz(r2, r3);
    h2 u2 = __builtin_amdgcn_cvt_pkrtz(r4, r5);
    h2 u3 = __builtin_amdgcn_cvt_pkrtz(r6, r7);
    x0 = packh(q0, q1, q2, q3);
    x1 = packh(u0, u1, u2, u3);
  };

  // one step: split both token-groups -> reload slots for chunk xc -> 8 LDS
  // frag reads (shared by both groups) -> 24 MFMA -> vmcnt(4) + RAW barrier.
  auto step = [&](v4f& s0, v4f& s1, v4f& s2, v4f& s3, int rb, int sc, int sb, int xc) {
    if (sc < 32) stage(sc, sb);
    f16x8 x0a, x1a, x0b, x1b;
    split(s0, s1, x0a, x1a);
    split(s2, s3, x0b, x1b);
    // slots dead: reload for chunk xc (2-step distance; dummy at tail)
    const float* n0 = xr0 + ((xc < 32) ? xc * 32 : 0);
    const float* n1 = xr1 + ((xc < 32) ? xc * 32 : 0);
    s0 = *(const v4f*)(n0);
    s1 = *(const v4f*)(n0 + 4);
    s2 = *(const v4f*)(n1);
    s3 = *(const v4f*)(n1 + 4);
    // 8 fragment reads from this wave's k-half (ds_read_b128, 1 KB each)
    f16x8 wf[2][4];
#pragma unroll
    for (int s = 0; s < 2; ++s)
#pragma unroll
      for (int t = 0; t < 4; ++t)
        wf[s][t] = ldh(&sh.wbuf[rb][kh][(s * 4 + t) * 512 + lane * 8]);
    // token-group 0: 3 passes (residuals into acc1, main into acc0)
#pragma unroll
    for (int t = 0; t < 4; ++t)
      acc1[0][t] = __builtin_amdgcn_mfma_f32_16x16x32_f16(wf[1][t], x0a, acc1[0][t], 0, 0, 0);
#pragma unroll
    for (int t = 0; t < 4; ++t)
      acc1[0][t] = __builtin_amdgcn_mfma_f32_16x16x32_f16(wf[0][t], x1a, acc1[0][t], 0, 0, 0);
#pragma unroll
    for (int t = 0; t < 4; ++t)
      acc0[0][t] = __builtin_amdgcn_mfma_f32_16x16x32_f16(wf[0][t], x0a, acc0[0][t], 0, 0, 0);
    // token-group 1
#pragma unroll
    for (int t = 0; t < 4; ++t)
      acc1[1][t] = __builtin_amdgcn_mfma_f32_16x16x32_f16(wf[1][t], x0b, acc1[1][t], 0, 0, 0);
#pragma unroll
    for (int t = 0; t < 4; ++t)
      acc1[1][t] = __builtin_amdgcn_mfma_f32_16x16x32_f16(wf[0][t], x1b, acc1[1][t], 0, 0, 0);
#pragma unroll
    for (int t = 0; t < 4; ++t)
      acc0[1][t] = __builtin_amdgcn_mfma_f32_16x16x32_f16(wf[0][t], x0b, acc0[1][t], 0, 0, 0);
    // counted wait: drains this step's 4 stage loads (oldest) + any older x
    // loads; leaves this step's 4 x loads in flight ACROSS the raw barrier.
    asm volatile("s_waitcnt vmcnt(4)" ::: "memory");
    __builtin_amdgcn_s_barrier();
    asm volatile("" ::: "memory");
  };

  // x slots: a* = even chunks, b* = odd chunks (2-step issue-to-use distance)
  v4f a0 = *(const v4f*)(xr0);
  v4f a1 = *(const v4f*)(xr0 + 4);
  v4f a2 = *(const v4f*)(xr1);
  v4f a3 = *(const v4f*)(xr1 + 4);
  v4f b0 = *(const v4f*)(xr0 + 32);
  v4f b1 = *(const v4f*)(xr0 + 36);
  v4f b2 = *(const v4f*)(xr1 + 32);
  v4f b3 = *(const v4f*)(xr1 + 36);

  stage(0, 0);
  asm volatile("s_waitcnt vmcnt(0)" ::: "memory");
  __syncthreads();

  for (int cc = 0; cc < 32; cc += 2) {
    step(a0, a1, a2, a3, 0, cc + 1, 1, cc + 2);   // chunk cc   (reads buf0)
    step(b0, b1, b2, b3, 1, cc + 2, 0, cc + 3);   // chunk cc+1 (reads buf1)
  }

  // ---- epilogue: combine splits, kh-reduce, logits -> LDS, fused routing ----
  float comb[2][4][4];
#pragma unroll
  for (int g = 0; g < 2; ++g)
#pragma unroll
    for (int t = 0; t < 4; ++t)
#pragma unroll
      for (int r = 0; r < 4; ++r)
        comb[g][t][r] = acc0[g][t][r] + acc1[g][t][r] * RINV;

  if (kh == 1) {
#pragma unroll
    for (int g = 0; g < 2; ++g)
#pragma unroll
      for (int t = 0; t < 4; ++t)
#pragma unroll
        for (int r = 0; r < 4; ++r)
          sh.ep.red[tp * 2 + g][t][r][lane] = comb[g][t][r];   // conflict-free
  }
  __syncthreads();
  if (kh == 0) {
#pragma unroll
    for (int g = 0; g < 2; ++g)
#pragma unroll
      for (int t = 0; t < 4; ++t)
#pragma unroll
        for (int r = 0; r < 4; ++r) {
          const float v = comb[g][t][r] + sh.ep.red[tp * 2 + g][t][r][lane];
          const int e = t * 16 + (lane >> 4) * 4 + r;
          sh.ep.lgt[e][(tp * 2 + g) * 16 + l15] = v;
        }
  }
  __syncthreads();

  // routing: thread tid<64 handles token blockIdx*64 + tid (R13-R18-verified)
  if (tid < 64) {
    const int row = blockIdx.x * 64 + tid;

    float sb[E_N];
#pragma unroll
    for (int e = 0; e < E_N; ++e)
      sb[e] = 1.f / (1.f + expf(-sh.ep.lgt[e][tid])) + bias[e];

    float gs[8];
#pragma unroll
    for (int g = 0; g < 8; ++g) {
      float m1 = -__builtin_inff(), m2 = -__builtin_inff();
#pragma unroll
      for (int j = 0; j < 8; ++j) {
        float v = sb[g * 8 + j];
        if (v > m1) { m2 = m1; m1 = v; }
        else if (v > m2) { m2 = v; }
      }
      gs[g] = m1 + m2;
    }

    unsigned gmask = 0;
#pragma unroll
    for (int tsel = 0; tsel < 4; ++tsel) {
      float best = -__builtin_inff(); int bi = 0;
#pragma unroll
      for (int g = 0; g < 8; ++g) {
        bool avail = ((gmask >> g) & 1u) == 0u;
        if (avail && gs[g] > best) { best = gs[g]; bi = g; }
      }
      gmask |= (1u << bi);
    }

    unsigned long long tm = 0ull;
#pragma unroll
    for (int g = 0; g < 8; ++g)
      if (((gmask >> g) & 1u) == 0u) tm |= (0xFFull << (8 * g));

    float wv[8]; int io[8]; float wsum = 0.f;
#pragma unroll
    for (int tsel = 0; tsel < 8; ++tsel) {
      float best = -__builtin_inff(); int bi = 0;
#pragma unroll
      for (int e = 0; e < E_N; ++e) {
        bool avail = ((tm >> e) & 1ull) == 0ull;
        if (avail && sb[e] > best) { best = sb[e]; bi = e; }
      }
      tm |= (1ull << bi);
      float sv = best - bias[bi];
      wv[tsel] = sv; io[tsel] = bi; wsum += sv;
    }

    const float scale = 2.5f / wsum;
    float4 w0 = make_float4(wv[0] * scale, wv[1] * scale, wv[2] * scale, wv[3] * scale);
    float4 w1 = make_float4(wv[4] * scale, wv[5] * scale, wv[6] * scale, wv[7] * scale);
    float4 i0 = make_float4((float)io[0], (float)io[1], (float)io[2], (float)io[3]);
    float4 i1 = make_float4((float)io[4], (float)io[5], (float)io[6], (float)io[7]);
    *(float4*)(out_w + (size_t)row * 8)     = w0;
    *(float4*)(out_w + (size_t)row * 8 + 4) = w1;
    *(float4*)(out_i + (size_t)row * 8)     = i0;
    *(float4*)(out_i + (size_t)row * 8 + 4) = i1;
  }
}

extern "C" void kernel_launch(void* const* d_in, const int* in_sizes, int n_in,
                              void* d_out, int out_size, void* d_ws, size_t ws_size,
                              hipStream_t stream) {
  const float* x    = (const float*)d_in[0];
  const float* wgt  = (const float*)d_in[1];
  const float* bias = (const float*)d_in[2];
  float* out = (float*)d_out;
  unsigned short* wlp = (unsigned short*)d_ws;

  k_prep  <<<WL_USHORTS / 256, 256, 0, stream>>>(wgt, wlp);
  k_logits<<<T_TOK / 64,       256, 0, stream>>>(x, wlp, bias,
                                                 out, out + (size_t)T_TOK * 8);
}